// Round 1
// baseline (1497.902 us; speedup 1.0000x reference)
//
#include <hip/hip_runtime.h>
#include <cstdint>
#include <cstddef>

typedef _Float16 f16;
typedef _Float16 f16x8 __attribute__((ext_vector_type(8)));
typedef _Float16 f16x4 __attribute__((ext_vector_type(4)));
typedef float    f32x4 __attribute__((ext_vector_type(4)));

#define MFMA16(a,b,c) __builtin_amdgcn_mfma_f32_16x16x32_f16((a),(b),(c),0,0,0)

__device__ __forceinline__ float lrelu(float v){ return v >= 0.f ? v : 0.2f*v; }

// ======================= prep kernels =======================

// convert 1x1 conv weights (C,C) fp32 -> fp16, same layout [co][ci]
__global__ __launch_bounds__(256) void k_prep1x1(
    const float* __restrict__ wq, const float* __restrict__ wk, const float* __restrict__ wv,
    f16* __restrict__ oq, f16* __restrict__ ok, f16* __restrict__ ov)
{
  int i = blockIdx.x*256 + threadIdx.x;      // 0 .. 196607
  int sel = i >> 16, r = i & 65535;
  const float* s = sel==0 ? wq : (sel==1 ? wk : wv);
  f16* d = sel==0 ? oq : (sel==1 ? ok : ov);
  d[r] = (f16)s[r];
}

// convert 3x3 conv weights (co,ci,3,3) fp32 -> fp16 layout [tap][co][ci]
__global__ __launch_bounds__(256) void k_prep3x3(
    const float* __restrict__ w0, const float* __restrict__ w1, const float* __restrict__ w2,
    f16* __restrict__ o0, f16* __restrict__ o1, f16* __restrict__ o2)
{
  int i = blockIdx.x*256 + threadIdx.x;      // 0 .. 1769471
  int sel = i / 589824;
  int r = i - sel*589824;
  int t = r >> 16; int rr = r & 65535; int co = rr >> 8; int ci = rr & 255;
  const float* s = sel==0 ? w0 : (sel==1 ? w1 : w2);
  f16* d = sel==0 ? o0 : (sel==1 ? o1 : o2);
  d[r] = (f16)s[(co*256 + ci)*9 + t];
}

// patch key-mask: pm[b*256+n] = 1.0 if mean of 4x4 patch of mask < 0.5 else 0.0
__global__ __launch_bounds__(256) void k_pmask(const float* __restrict__ mask, float* __restrict__ pm)
{
  int t = blockIdx.x*256 + threadIdx.x;      // 0..4095
  int b = t >> 8, n = t & 255;
  int y0 = (n>>4)<<2, x0 = (n&15)<<2;
  const float* mb = mask + b*4096;
  float s = 0.f;
  #pragma unroll
  for (int i=0;i<4;++i)
    #pragma unroll
    for (int j=0;j<4;++j) s += mb[(y0+i)*64 + x0+j];
  pm[t] = (s*(1.f/16.f) < 0.5f) ? 1.f : 0.f;
}

// ======================= QKV 1x1-conv GEMM =======================
// grid: ((sel*16 + b)*4 + cot)*64 + y   ; block 256 (4 waves)
// computes 64 co x 64 px (one image row) per workgroup; writes patchified fp16
__global__ __launch_bounds__(256) void k_qkv(
    const float* __restrict__ x,
    const f16* __restrict__ wq, const f16* __restrict__ wk, const f16* __restrict__ wv,
    const float* __restrict__ bq, const float* __restrict__ bk, const float* __restrict__ bv,
    const float* __restrict__ nq, const float* __restrict__ nk, const float* __restrict__ nv,
    f16* __restrict__ Qp, f16* __restrict__ Kp, f16* __restrict__ Vt)
{
  int idx = blockIdx.x;
  int y   = idx & 63; idx >>= 6;
  int cot = idx & 3;  idx >>= 2;
  int b   = idx & 15; idx >>= 4;
  int sel = idx;                       // 0=q 1=k 2=v
  int tid = threadIdx.x;
  int wave = tid>>6, lane = tid&63, quad = lane>>4, l16 = lane&15;
  int co0 = cot*64;

  const f16*  W    = sel==0 ? wq : (sel==1 ? wk : wv);
  const float* bias= sel==0 ? bq : (sel==1 ? bk : bv);
  const float* nz  = sel==0 ? nq : (sel==1 ? nk : nv);

  __shared__ f16 Al[64*40];
  __shared__ f16 Bl[64*40];

  f32x4 acc[4];
  #pragma unroll
  for (int i=0;i<4;++i){ acc[i][0]=0.f; acc[i][1]=0.f; acc[i][2]=0.f; acc[i][3]=0.f; }

  const float* xb = x + (size_t)b*256*4096 + y*64;
  int aco = tid>>2,  ap  = (tid&3)*8;
  int bci = tid>>3,  bx0 = (tid&7)*8;

  for (int kk=0;kk<8;++kk){
    int ci0 = kk*32;
    *(uint4*)&Al[aco*40+ap] = *(const uint4*)&W[(co0+aco)*256 + ci0 + ap];
    {
      const float* s = xb + (size_t)(ci0+bci)*4096 + bx0;
      float4 v0 = *(const float4*)s;
      float4 v1 = *(const float4*)(s+4);
      f16* d = &Bl[bci];
      d[(bx0+0)*40] = (f16)v0.x; d[(bx0+1)*40] = (f16)v0.y;
      d[(bx0+2)*40] = (f16)v0.z; d[(bx0+3)*40] = (f16)v0.w;
      d[(bx0+4)*40] = (f16)v1.x; d[(bx0+5)*40] = (f16)v1.y;
      d[(bx0+6)*40] = (f16)v1.z; d[(bx0+7)*40] = (f16)v1.w;
    }
    __syncthreads();
    f16x8 af = *(const f16x8*)&Al[(wave*16+l16)*40 + quad*8];
    #pragma unroll
    for (int mt=0;mt<4;++mt){
      f16x8 bf = *(const f16x8*)&Bl[(mt*16+l16)*40 + quad*8];
      acc[mt] = MFMA16(af, bf, acc[mt]);
    }
    __syncthreads();
  }

  int cobase = co0 + wave*16 + quad*4;
  #pragma unroll
  for (int mt=0;mt<4;++mt){
    int xx = mt*16 + l16;
    #pragma unroll
    for (int r=0;r<4;++r){
      int co = cobase + r;
      float v = acc[mt][r] + bias[co] + nz[((b*256 + co)*64 + y)*64 + xx];
      f16 hv = (f16)v;
      int n  = ((y>>2)<<4) + (xx>>2);
      int dd = ((co&15)<<4) + ((y&3)<<2) + (xx&3);
      int h  = co>>4;
      int base = (b*16 + h)<<16;
      if (sel==2)      Vt[base + (dd<<8) + n] = hv;   // V transposed: [dd][m]
      else if (sel==0) Qp[base + (n<<8) + dd] = hv;
      else             Kp[base + (n<<8) + dd] = hv;
    }
  }
}

// ======================= attention =======================
// grid: ((b*16 + h)*4 + nt)  ; block 256 (4 waves). 64 query rows per wg.
__global__ __launch_bounds__(256) void k_attn(
    const f16* __restrict__ Qp, const f16* __restrict__ Kp, const f16* __restrict__ Vt,
    const float* __restrict__ dis, const float* __restrict__ lap_a,
    const float* __restrict__ pm, f16* __restrict__ attn)
{
  int idx = blockIdx.x;
  int nt = idx & 3; idx >>= 2;
  int h  = idx & 15; idx >>= 4;
  int b  = idx;
  int tid = threadIdx.x, wave = tid>>6, lane = tid&63, quad = lane>>4, l16 = lane&15;
  int n0 = nt*64;
  int bh = (b*16 + h) << 16;

  __shared__ f16 Ql[64*264];   // Q tile, later reused for P
  __shared__ f16 KVl[32*264];  // K / V chunks

  // stage Q tile (64 rows x 256)
  {
    int row = tid>>2, part = (tid&3)*64;
    const uint4* s = (const uint4*)&Qp[bh + ((n0+row)<<8) + part];
    uint4* d = (uint4*)&Ql[row*264 + part];
    #pragma unroll
    for (int j=0;j<8;++j) d[j] = s[j];
  }

  float splus = log1pf(expf(lap_a[0]));

  f32x4 sacc[16];
  #pragma unroll
  for (int i=0;i<16;++i){ sacc[i][0]=0.f; sacc[i][1]=0.f; sacc[i][2]=0.f; sacc[i][3]=0.f; }

  // S = Q K^T : loop over 8 chunks of 32 keys
  #pragma unroll
  for (int mc=0; mc<8; ++mc){
    __syncthreads();
    {
      int row = tid>>3, part = (tid&7)*32;
      const uint4* s = (const uint4*)&Kp[bh + ((mc*32+row)<<8) + part];
      uint4* d = (uint4*)&KVl[row*264 + part];
      #pragma unroll
      for (int j=0;j<4;++j) d[j] = s[j];
    }
    __syncthreads();
    #pragma unroll
    for (int kk=0;kk<8;++kk){
      f16x8 af = *(const f16x8*)&Ql[(wave*16+l16)*264 + kk*32 + quad*8];
      #pragma unroll
      for (int j=0;j<2;++j){
        f16x8 bf = *(const f16x8*)&KVl[(j*16+l16)*264 + kk*32 + quad*8];
        sacc[mc*2+j] = MFMA16(af, bf, sacc[mc*2+j]);
      }
    }
  }

  // scores -> softmax -> P (fp16) into Ql (own-wave rows only)
  int nrow_base = wave*16 + quad*4;
  float pmv[16];
  #pragma unroll
  for (int t=0;t<16;++t) pmv[t] = pm[b*256 + t*16 + l16];

  #pragma unroll
  for (int r=0;r<4;++r){
    int n = n0 + nrow_base + r;
    float sv[16];
    float mx = -1e30f;
    #pragma unroll
    for (int t=0;t<16;++t){
      float s = sacc[t][r];
      s = (s + splus * dis[n*256 + t*16 + l16]) * 0.0625f;
      s = (pmv[t] > 0.5f) ? -1e30f : s;
      sv[t] = s;
      mx = fmaxf(mx, s);
    }
    #pragma unroll
    for (int off=1; off<16; off<<=1) mx = fmaxf(mx, __shfl_xor(mx, off, 64));
    float sum = 0.f;
    #pragma unroll
    for (int t=0;t<16;++t){ float e = __expf(sv[t]-mx); sv[t]=e; sum += e; }
    #pragma unroll
    for (int off=1; off<16; off<<=1) sum += __shfl_xor(sum, off, 64);
    float inv = 1.f/sum;
    #pragma unroll
    for (int t=0;t<16;++t) Ql[(nrow_base + r)*264 + t*16 + l16] = (f16)(sv[t]*inv);
  }

  // O = P V : loop over 8 chunks of 32 dd columns (V stored transposed [dd][m])
  for (int dc=0; dc<8; ++dc){
    __syncthreads();
    {
      int row = tid>>3, part = (tid&7)*32;
      const uint4* s = (const uint4*)&Vt[bh + ((dc*32+row)<<8) + part];
      uint4* d = (uint4*)&KVl[row*264 + part];
      #pragma unroll
      for (int j=0;j<4;++j) d[j] = s[j];
    }
    __syncthreads();
    f32x4 oacc[2];
    #pragma unroll
    for (int i=0;i<2;++i){ oacc[i][0]=0.f; oacc[i][1]=0.f; oacc[i][2]=0.f; oacc[i][3]=0.f; }
    #pragma unroll
    for (int kk=0;kk<8;++kk){
      f16x8 af = *(const f16x8*)&Ql[(wave*16+l16)*264 + kk*32 + quad*8];
      #pragma unroll
      for (int j=0;j<2;++j){
        f16x8 bf = *(const f16x8*)&KVl[(j*16+l16)*264 + kk*32 + quad*8];
        oacc[j] = MFMA16(af, bf, oacc[j]);
      }
    }
    // unpatchify store
    #pragma unroll
    for (int j=0;j<2;++j){
      int dd = dc*32 + j*16 + l16;
      int c  = h*16 + (dd>>4);
      int pi = (dd>>2)&3, pj = dd&3;
      #pragma unroll
      for (int r=0;r<4;++r){
        int n  = n0 + nrow_base + r;
        int yy = ((n>>4)<<2) + pi;
        int xx = ((n&15)<<2) + pj;
        attn[((b*256 + c)*64 + yy)*64 + xx] = (f16)oacc[j][r];
      }
    }
  }
}

// ======================= 3x3 conv (implicit GEMM) =======================
// grid: (b*4 + cot)*64 + y ; block 256. 64 co x 64 px (one row).
// mode 0: v=lrelu(v+bias)+resid -> outf & outbf ; mode!=0: v=v+bias -> outf
__global__ __launch_bounds__(256) void k_conv3(
    const f16* __restrict__ in, const f16* __restrict__ Wt, const float* __restrict__ bias,
    const float* __restrict__ resid, float* __restrict__ outf, f16* __restrict__ outbf,
    int dil, int mode)
{
  int idx = blockIdx.x;
  int y   = idx & 63; idx >>= 6;
  int cot = idx & 3;  idx >>= 2;
  int b   = idx;
  int co0 = cot*64;
  int tid = threadIdx.x;
  int wave = tid>>6, lane = tid&63, quad = lane>>4, l16 = lane&15;

  __shared__ f16 Al[3*64*40];   // A tiles for 3 kx taps
  __shared__ f16 Bl[68*40];     // input rows, transposed [x'][ci], halo = dil each side

  f32x4 acc[4];
  #pragma unroll
  for (int i=0;i<4;++i){ acc[i][0]=0.f; acc[i][1]=0.f; acc[i][2]=0.f; acc[i][3]=0.f; }

  const f16* inb = in + (size_t)b*256*4096;
  int aco = tid>>2,  ap  = (tid&3)*8;
  int bci = tid>>3,  bx0 = (tid&7)*8;
  int tail = 2*dil*32;

  for (int ky=0; ky<3; ++ky){
    int yy = y + dil*(ky-1);
    bool yok = (yy>=0) && (yy<64);
    for (int kc=0; kc<8; ++kc){
      int ci0 = kc*32;
      // A: 3 taps of [64co x 32ci]
      #pragma unroll
      for (int kx=0;kx<3;++kx)
        *(uint4*)&Al[kx*2560 + aco*40 + ap] =
            *(const uint4*)&Wt[((ky*3+kx)<<16) + ((co0+aco)<<8) + ci0 + ap];
      // B: transposed staging with halo; x' = xx + dil
      {
        const f16* src = inb + (size_t)(ci0+bci)*4096 + yy*64;
        #pragma unroll
        for (int j=0;j<8;++j){
          int xp = bx0 + j;
          int xx = xp - dil;
          f16 v = (yok && xx>=0) ? src[xx] : (f16)0.f;
          Bl[xp*40 + bci] = v;
        }
        if (tid < tail){
          int ci2 = tid & 31, xp = 64 + (tid>>5);
          int xx = xp - dil;
          f16 v = (yok && xx<64) ? inb[(size_t)(ci0+ci2)*4096 + yy*64 + xx] : (f16)0.f;
          Bl[xp*40 + ci2] = v;
        }
      }
      __syncthreads();
      #pragma unroll
      for (int kx=0;kx<3;++kx){
        f16x8 af = *(const f16x8*)&Al[kx*2560 + (wave*16+l16)*40 + quad*8];
        #pragma unroll
        for (int mt=0;mt<4;++mt){
          f16x8 bf = *(const f16x8*)&Bl[(mt*16 + l16 + dil*kx)*40 + quad*8];
          acc[mt] = MFMA16(af, bf, acc[mt]);
        }
      }
      __syncthreads();
    }
  }

  int cobase = co0 + wave*16 + quad*4;
  #pragma unroll
  for (int mt=0;mt<4;++mt){
    int xx = mt*16 + l16;
    #pragma unroll
    for (int r=0;r<4;++r){
      int co = cobase + r;
      float v = acc[mt][r] + bias[co];
      int o = ((b*256 + co)*64 + y)*64 + xx;
      if (mode==0){
        v = lrelu(v) + resid[o];
        outf[o] = v;
        outbf[o] = (f16)v;
      } else {
        outf[o] = v;
      }
    }
  }
}

// ======================= instance-norm stats =======================
__global__ __launch_bounds__(256) void k_instats(const float* __restrict__ v, float2* __restrict__ st)
{
  int bc = blockIdx.x;
  const float* p = v + (size_t)bc*4096;
  int tid = threadIdx.x;
  float s=0.f, ss=0.f;
  #pragma unroll
  for (int it=0; it<4; ++it){
    float4 u = *(const float4*)(p + it*1024 + tid*4);
    s  += u.x+u.y+u.z+u.w;
    ss += u.x*u.x + u.y*u.y + u.z*u.z + u.w*u.w;
  }
  #pragma unroll
  for (int off=32; off; off>>=1){ s += __shfl_down(s, off, 64); ss += __shfl_down(ss, off, 64); }
  __shared__ float rs[4], rss[4];
  int wave = tid>>6, lane = tid&63;
  if (lane==0){ rs[wave]=s; rss[wave]=ss; }
  __syncthreads();
  if (tid==0){
    float S = rs[0]+rs[1]+rs[2]+rs[3], SS = rss[0]+rss[1]+rss[2]+rss[3];
    float mu = S*(1.f/4096.f);
    float var = SS*(1.f/4096.f) - mu*mu;
    st[bc] = make_float2(mu, rsqrtf(var + 1e-5f));
  }
}

// normalize + lrelu -> fp16 (input to next conv)
__global__ __launch_bounds__(256) void k_norm(const float* __restrict__ v, const float2* __restrict__ st,
                                              f16* __restrict__ o)
{
  int i4 = blockIdx.x*256 + threadIdx.x;
  float2 s = st[i4>>10];
  float4 u = *(const float4*)(v + (size_t)i4*4);
  f16x4 r;
  r[0] = (f16)lrelu((u.x - s.x)*s.y);
  r[1] = (f16)lrelu((u.y - s.x)*s.y);
  r[2] = (f16)lrelu((u.z - s.x)*s.y);
  r[3] = (f16)lrelu((u.w - s.x)*s.y);
  *(f16x4*)(o + (size_t)i4*4) = r;
}

// final: out += lrelu(IN(c2))
__global__ __launch_bounds__(256) void k_final(float* __restrict__ out, const float* __restrict__ c2,
                                               const float2* __restrict__ st)
{
  int i4 = blockIdx.x*256 + threadIdx.x;
  float2 s = st[i4>>10];
  float4 u = *(const float4*)(c2 + (size_t)i4*4);
  float4 o = *(const float4*)(out + (size_t)i4*4);
  o.x += lrelu((u.x - s.x)*s.y);
  o.y += lrelu((u.y - s.x)*s.y);
  o.z += lrelu((u.z - s.x)*s.y);
  o.w += lrelu((u.w - s.x)*s.y);
  *(float4*)(out + (size_t)i4*4) = o;
}

// ======================= launch =======================
extern "C" void kernel_launch(void* const* d_in, const int* in_sizes, int n_in,
                              void* d_out, int out_size, void* d_ws, size_t ws_size,
                              hipStream_t stream)
{
  const float* x    = (const float*)d_in[0];
  const float* mask = (const float*)d_in[1];
  const float* dis  = (const float*)d_in[2];
  const float* lapa = (const float*)d_in[3];
  const float* Wq   = (const float*)d_in[4];
  const float* bq   = (const float*)d_in[5];
  const float* Wk   = (const float*)d_in[6];
  const float* bk   = (const float*)d_in[7];
  const float* Wv   = (const float*)d_in[8];
  const float* bv   = (const float*)d_in[9];
  const float* nq   = (const float*)d_in[10];
  const float* nk   = (const float*)d_in[11];
  const float* nv   = (const float*)d_in[12];
  const float* Wo   = (const float*)d_in[13];
  const float* bo   = (const float*)d_in[14];
  const float* W1   = (const float*)d_in[15];
  const float* b1   = (const float*)d_in[16];
  const float* W2   = (const float*)d_in[17];
  const float* b2   = (const float*)d_in[18];

  char* w = (char*)d_ws;
  f16*   Qp    = (f16*)(w + 0);            // 33554432
  f16*   Kp    = (f16*)(w + 33554432);     // 33554432
  f16*   Vt    = (f16*)(w + 67108864);     // 33554432
  f16*   attn  = (f16*)(w + 100663296);    // 33554432
  f16*   outbf = (f16*)(w + 134217728);    // 33554432
  float* c1    = (float*)(w + 0);          // alias Qp+Kp (dead after attention)
  f16*   y1    = (f16*)(w + 67108864);     // alias Vt
  float* c2    = (float*)(w + 0);          // alias c1 (dead after norm)
  f16*   wqh   = (f16*)(w + 167772160);
  f16*   wkh   = wqh + 65536;
  f16*   wvh   = wkh + 65536;
  f16*   wt0   = (f16*)(w + 168165376);
  f16*   wt1   = wt0 + 589824;
  f16*   wt2   = wt1 + 589824;
  float* pmk   = (float*)(w + 171704320);
  float2* st1  = (float2*)(w + 171720704);
  float2* st2  = (float2*)(w + 171753472);
  float* out   = (float*)d_out;

  k_prep1x1<<<768, 256, 0, stream>>>(Wq, Wk, Wv, wqh, wkh, wvh);
  k_prep3x3<<<6912, 256, 0, stream>>>(Wo, W1, W2, wt0, wt1, wt2);
  k_pmask<<<16, 256, 0, stream>>>(mask, pmk);
  k_qkv<<<12288, 256, 0, stream>>>(x, wqh, wkh, wvh, bq, bk, bv, nq, nk, nv, Qp, Kp, Vt);
  k_attn<<<1024, 256, 0, stream>>>(Qp, Kp, Vt, dis, lapa, pmk, attn);
  k_conv3<<<4096, 256, 0, stream>>>(attn, wt0, bo, x, out, outbf, 1, 0);
  k_conv3<<<4096, 256, 0, stream>>>(outbf, wt1, b1, nullptr, c1, nullptr, 2, 1);
  k_instats<<<4096, 256, 0, stream>>>(c1, st1);
  k_norm<<<16384, 256, 0, stream>>>(c1, st1, y1);
  k_conv3<<<4096, 256, 0, stream>>>(y1, wt2, b2, nullptr, c2, nullptr, 1, 2);
  k_instats<<<4096, 256, 0, stream>>>(c2, st2);
  k_final<<<16384, 256, 0, stream>>>(out, c2, st2);
}

// Round 2
// 1233.737 us; speedup vs baseline: 1.2141x; 1.2141x over previous
//
#include <hip/hip_runtime.h>
#include <cstdint>
#include <cstddef>

typedef _Float16 f16;
typedef _Float16 f16x8 __attribute__((ext_vector_type(8)));
typedef _Float16 f16x4 __attribute__((ext_vector_type(4)));
typedef float    f32x4 __attribute__((ext_vector_type(4)));

#define MFMA16(a,b,c) __builtin_amdgcn_mfma_f32_16x16x32_f16((a),(b),(c),0,0,0)

__device__ __forceinline__ float lrelu(float v){ return v >= 0.f ? v : 0.2f*v; }

// ======================= prep kernels =======================

__global__ __launch_bounds__(256) void k_prep1x1(
    const float* __restrict__ wq, const float* __restrict__ wk, const float* __restrict__ wv,
    f16* __restrict__ oq, f16* __restrict__ ok, f16* __restrict__ ov)
{
  int i = blockIdx.x*256 + threadIdx.x;
  int sel = i >> 16, r = i & 65535;
  const float* s = sel==0 ? wq : (sel==1 ? wk : wv);
  f16* d = sel==0 ? oq : (sel==1 ? ok : ov);
  d[r] = (f16)s[r];
}

// 3x3 conv weights (co,ci,3,3) fp32 -> fp16 layout [tap][co][ci]
__global__ __launch_bounds__(256) void k_prep3x3(
    const float* __restrict__ w0, const float* __restrict__ w1, const float* __restrict__ w2,
    f16* __restrict__ o0, f16* __restrict__ o1, f16* __restrict__ o2)
{
  int i = blockIdx.x*256 + threadIdx.x;
  int sel = i / 589824;
  int r = i - sel*589824;
  int t = r >> 16; int rr = r & 65535; int co = rr >> 8; int ci = rr & 255;
  const float* s = sel==0 ? w0 : (sel==1 ? w1 : w2);
  f16* d = sel==0 ? o0 : (sel==1 ? o1 : o2);
  d[r] = (f16)s[(co*256 + ci)*9 + t];
}

__global__ __launch_bounds__(256) void k_pmask(const float* __restrict__ mask, float* __restrict__ pm)
{
  int t = blockIdx.x*256 + threadIdx.x;
  int b = t >> 8, n = t & 255;
  int y0 = (n>>4)<<2, x0 = (n&15)<<2;
  const float* mb = mask + b*4096;
  float s = 0.f;
  #pragma unroll
  for (int i=0;i<4;++i)
    #pragma unroll
    for (int j=0;j<4;++j) s += mb[(y0+i)*64 + x0+j];
  pm[t] = (s*(1.f/16.f) < 0.5f) ? 1.f : 0.f;
}

// ======================= NCHW f32 -> NHWC f16 (optional IN+lrelu) ===========
// grid: b*64 + y ; block 256
__global__ __launch_bounds__(256) void k_nchw2nhwc(
    const float* __restrict__ src, const float2* __restrict__ st, f16* __restrict__ dst)
{
  int idx = blockIdx.x;
  int y = idx & 63, b = idx >> 6;
  int tid = threadIdx.x;
  __shared__ f16 T[64*264];

  // phase 1: thread = channel; read its 64-px row, scatter into LDS [x][c]
  {
    const float* row = src + (size_t)(b*256+tid)*4096 + y*64;
    float mu = 0.f, ri = 1.f;
    bool doin = (st != nullptr);
    if (doin){ float2 s = st[b*256+tid]; mu = s.x; ri = s.y; }
    #pragma unroll
    for (int j=0;j<16;++j){
      float4 u = *(const float4*)(row + j*4);
      int x = j*4;
      float a0=(u.x-mu)*ri, a1=(u.y-mu)*ri, a2=(u.z-mu)*ri, a3=(u.w-mu)*ri;
      if (doin){ a0=lrelu(a0); a1=lrelu(a1); a2=lrelu(a2); a3=lrelu(a3); }
      T[(x+0)*264+tid]=(f16)a0; T[(x+1)*264+tid]=(f16)a1;
      T[(x+2)*264+tid]=(f16)a2; T[(x+3)*264+tid]=(f16)a3;
    }
  }
  __syncthreads();
  // phase 2: vectorized NHWC store
  {
    int oct = tid & 31, pxl = tid >> 5;
    #pragma unroll
    for (int p=0;p<8;++p){
      int px = p*8 + pxl;
      *(uint4*)&dst[((size_t)((b*64+y)*64+px)<<8) + oct*8] = *(const uint4*)&T[px*264 + oct*8];
    }
  }
}

// ======================= QKV 1x1-conv GEMM (NHWC input) =======================
// grid: ((sel*16 + b)*4 + cot)*16 + yt ; block 256. 64co x (4y x 64x).
__global__ __launch_bounds__(256) void k_qkv(
    const f16* __restrict__ xh,
    const f16* __restrict__ wq, const f16* __restrict__ wk, const f16* __restrict__ wv,
    const float* __restrict__ bq, const float* __restrict__ bk, const float* __restrict__ bv,
    const float* __restrict__ nq, const float* __restrict__ nk, const float* __restrict__ nv,
    f16* __restrict__ Qp, f16* __restrict__ Kp, f16* __restrict__ Vt)
{
  int idx = blockIdx.x;
  int yt  = idx & 15; idx >>= 4;
  int cot = idx & 3;  idx >>= 2;
  int b   = idx & 15; idx >>= 4;
  int sel = idx;
  int tid = threadIdx.x;
  int wave = tid>>6, lane = tid&63, quad = lane>>4, l16 = lane&15;
  int co0 = cot*64, y0 = yt*4;

  const f16*  W    = sel==0 ? wq : (sel==1 ? wk : wv);
  const float* bias= sel==0 ? bq : (sel==1 ? bk : bv);
  const float* nz  = sel==0 ? nq : (sel==1 ? nk : nv);

  __shared__ f16 Al[64*40];
  __shared__ f16 Bl[256*32];

  f32x4 acc[16];
  #pragma unroll
  for (int i=0;i<16;++i){ acc[i][0]=0.f; acc[i][1]=0.f; acc[i][2]=0.f; acc[i][3]=0.f; }

  for (int kc=0;kc<8;++kc){
    int ci0 = kc*32;
    {
      int aco = tid>>2, ap = (tid&3)*8;
      *(uint4*)&Al[aco*40+ap] = *(const uint4*)&W[((co0+aco)<<8) + ci0 + ap];
    }
    #pragma unroll
    for (int p=0;p<4;++p){
      int i = p*256 + tid;
      int px = i>>2, oct = i&3;
      uint4 v = *(const uint4*)&xh[((size_t)((b*64 + y0 + (px>>6))*64 + (px&63))<<8) + ci0 + oct*8];
      *(uint4*)&Bl[px*32 + ((oct ^ (px&3))<<3)] = v;
    }
    __syncthreads();
    f16x8 af = *(const f16x8*)&Al[(wave*16+l16)*40 + quad*8];
    #pragma unroll
    for (int nt=0;nt<16;++nt){
      int bidx = (nt>>2)*64 + (nt&3)*16 + l16;
      f16x8 bf = *(const f16x8*)&Bl[bidx*32 + ((quad ^ (bidx&3))<<3)];
      acc[nt] = MFMA16(af, bf, acc[nt]);
    }
    __syncthreads();
  }

  int cob = co0 + wave*16 + quad*4;
  int bh_base = (b*16) << 16;
  #pragma unroll
  for (int nt=0;nt<16;++nt){
    int y = y0 + (nt>>2), x = (nt&3)*16 + l16;
    #pragma unroll
    for (int r=0;r<4;++r){
      int co = cob + r;
      float v = acc[nt][r] + bias[co] + nz[(size_t)(b*256+co)*4096 + y*64 + x];
      f16 hv = (f16)v;
      int n  = ((y>>2)<<4) + (x>>2);
      int dd = ((co&15)<<4) + ((y&3)<<2) + (x&3);
      int h  = co>>4;
      int base = bh_base + (h<<16);
      if (sel==2)      Vt[base + (dd<<8) + n] = hv;
      else if (sel==0) Qp[base + (n<<8) + dd] = hv;
      else             Kp[base + (n<<8) + dd] = hv;
    }
  }
}

// ======================= attention =======================
__global__ __launch_bounds__(256) void k_attn(
    const f16* __restrict__ Qp, const f16* __restrict__ Kp, const f16* __restrict__ Vt,
    const float* __restrict__ dis, const float* __restrict__ lap_a,
    const float* __restrict__ pm, f16* __restrict__ attn)
{
  int idx = blockIdx.x;
  int nt = idx & 3; idx >>= 2;
  int h  = idx & 15; idx >>= 4;
  int b  = idx;
  int tid = threadIdx.x, wave = tid>>6, lane = tid&63, quad = lane>>4, l16 = lane&15;
  int n0 = nt*64;
  int bh = (b*16 + h) << 16;

  __shared__ f16 Ql[64*264];
  __shared__ f16 KVl[32*264];

  {
    int row = tid>>2, part = (tid&3)*64;
    const uint4* s = (const uint4*)&Qp[bh + ((n0+row)<<8) + part];
    uint4* d = (uint4*)&Ql[row*264 + part];
    #pragma unroll
    for (int j=0;j<8;++j) d[j] = s[j];
  }

  float splus = log1pf(expf(lap_a[0]));

  f32x4 sacc[16];
  #pragma unroll
  for (int i=0;i<16;++i){ sacc[i][0]=0.f; sacc[i][1]=0.f; sacc[i][2]=0.f; sacc[i][3]=0.f; }

  #pragma unroll
  for (int mc=0; mc<8; ++mc){
    __syncthreads();
    {
      int row = tid>>3, part = (tid&7)*32;
      const uint4* s = (const uint4*)&Kp[bh + ((mc*32+row)<<8) + part];
      uint4* d = (uint4*)&KVl[row*264 + part];
      #pragma unroll
      for (int j=0;j<4;++j) d[j] = s[j];
    }
    __syncthreads();
    #pragma unroll
    for (int kk=0;kk<8;++kk){
      f16x8 af = *(const f16x8*)&Ql[(wave*16+l16)*264 + kk*32 + quad*8];
      #pragma unroll
      for (int j=0;j<2;++j){
        f16x8 bf = *(const f16x8*)&KVl[(j*16+l16)*264 + kk*32 + quad*8];
        sacc[mc*2+j] = MFMA16(af, bf, sacc[mc*2+j]);
      }
    }
  }

  int nrow_base = wave*16 + quad*4;
  float pmv[16];
  #pragma unroll
  for (int t=0;t<16;++t) pmv[t] = pm[b*256 + t*16 + l16];

  #pragma unroll
  for (int r=0;r<4;++r){
    int n = n0 + nrow_base + r;
    float sv[16];
    float mx = -1e30f;
    #pragma unroll
    for (int t=0;t<16;++t){
      float s = sacc[t][r];
      s = (s + splus * dis[n*256 + t*16 + l16]) * 0.0625f;
      s = (pmv[t] > 0.5f) ? -1e30f : s;
      sv[t] = s;
      mx = fmaxf(mx, s);
    }
    #pragma unroll
    for (int off=1; off<16; off<<=1) mx = fmaxf(mx, __shfl_xor(mx, off, 64));
    float sum = 0.f;
    #pragma unroll
    for (int t=0;t<16;++t){ float e = __expf(sv[t]-mx); sv[t]=e; sum += e; }
    #pragma unroll
    for (int off=1; off<16; off<<=1) sum += __shfl_xor(sum, off, 64);
    float inv = 1.f/sum;
    #pragma unroll
    for (int t=0;t<16;++t) Ql[(nrow_base + r)*264 + t*16 + l16] = (f16)(sv[t]*inv);
  }

  for (int dc=0; dc<8; ++dc){
    __syncthreads();
    {
      int row = tid>>3, part = (tid&7)*32;
      const uint4* s = (const uint4*)&Vt[bh + ((dc*32+row)<<8) + part];
      uint4* d = (uint4*)&KVl[row*264 + part];
      #pragma unroll
      for (int j=0;j<4;++j) d[j] = s[j];
    }
    __syncthreads();
    f32x4 oacc[2];
    #pragma unroll
    for (int i=0;i<2;++i){ oacc[i][0]=0.f; oacc[i][1]=0.f; oacc[i][2]=0.f; oacc[i][3]=0.f; }
    #pragma unroll
    for (int kk=0;kk<8;++kk){
      f16x8 af = *(const f16x8*)&Ql[(wave*16+l16)*264 + kk*32 + quad*8];
      #pragma unroll
      for (int j=0;j<2;++j){
        f16x8 bf = *(const f16x8*)&KVl[(j*16+l16)*264 + kk*32 + quad*8];
        oacc[j] = MFMA16(af, bf, oacc[j]);
      }
    }
    #pragma unroll
    for (int j=0;j<2;++j){
      int dd = dc*32 + j*16 + l16;
      int c  = h*16 + (dd>>4);
      int pi = (dd>>2)&3, pj = dd&3;
      #pragma unroll
      for (int r=0;r<4;++r){
        int n  = n0 + nrow_base + r;
        int yy = ((n>>4)<<2) + pi;
        int xx = ((n&15)<<2) + pj;
        attn[((size_t)((b*64+yy)*64+xx)<<8) + c] = (f16)oacc[j][r];  // NHWC
      }
    }
  }
}

// ======================= 3x3 conv (implicit GEMM, NHWC input) ================
// grid: (b*4 + cot)*16 + yt ; block 256. 64co x (4y x 64x) per block.
template<int DIL, int MODE>
__global__ __launch_bounds__(256) void k_conv3(
    const f16* __restrict__ in, const f16* __restrict__ Wt, const float* __restrict__ bias,
    const float* __restrict__ resid, float* __restrict__ outf, f16* __restrict__ outh)
{
  int idx = blockIdx.x;
  int yt  = idx & 15; idx >>= 4;
  int cot = idx & 3;  idx >>= 2;
  int b   = idx;
  int y0 = yt*4, co0 = cot*64;
  int tid = threadIdx.x;
  int wave = tid>>6, lane = tid&63, quad = lane>>4, l16 = lane&15;

  __shared__ f16 Al[3*64*40];   // 3 kx taps, stride-40 rows
  __shared__ f16 Bl[4*68*32];   // 4 input rows with x-halo, 32ci, oct-swizzled

  f32x4 acc[16];
  #pragma unroll
  for (int i=0;i<16;++i){ acc[i][0]=0.f; acc[i][1]=0.f; acc[i][2]=0.f; acc[i][3]=0.f; }

  constexpr int PXR = 64 + 2*DIL;
  constexpr int NU4 = 16*PXR;

  for (int ky=0; ky<3; ++ky){
    int yb = y0 + DIL*(ky-1);
    for (int kc=0; kc<8; ++kc){
      int ci0 = kc*32;
      {
        int aco = tid>>2, ap = (tid&3)*8;
        #pragma unroll
        for (int kx=0;kx<3;++kx)
          *(uint4*)&Al[kx*2560 + aco*40 + ap] =
              *(const uint4*)&Wt[((ky*3+kx)<<16) + ((co0+aco)<<8) + ci0 + ap];
      }
      #pragma unroll
      for (int p=0;p<5;++p){
        int i = p*256 + tid;
        if (i < NU4){
          int px = i>>2, oct = i&3;
          int yr = px / PXR, xp = px - yr*PXR;
          int yy = yb + yr, xx = xp - DIL;
          uint4 v = make_uint4(0u,0u,0u,0u);
          if (yy>=0 && yy<64 && xx>=0 && xx<64)
            v = *(const uint4*)&in[((size_t)((b*64+yy)*64+xx)<<8) + ci0 + oct*8];
          int si = yr*68 + xp;
          *(uint4*)&Bl[si*32 + ((oct ^ (si&3))<<3)] = v;
        }
      }
      __syncthreads();
      #pragma unroll
      for (int kx=0;kx<3;++kx){
        f16x8 af = *(const f16x8*)&Al[kx*2560 + (wave*16+l16)*40 + quad*8];
        #pragma unroll
        for (int nt=0;nt<16;++nt){
          int bidx = (nt>>2)*68 + (nt&3)*16 + l16 + kx*DIL;
          f16x8 bf = *(const f16x8*)&Bl[bidx*32 + ((quad ^ (bidx&3))<<3)];
          acc[nt] = MFMA16(af, bf, acc[nt]);
        }
      }
      __syncthreads();
    }
  }

  int cob = co0 + wave*16 + quad*4;
  float bs[4];
  #pragma unroll
  for (int r=0;r<4;++r) bs[r] = bias[cob+r];
  #pragma unroll
  for (int nt=0;nt<16;++nt){
    int y = y0 + (nt>>2), x = (nt&3)*16 + l16;
    #pragma unroll
    for (int r=0;r<4;++r){
      int co = cob + r;
      float v = acc[nt][r] + bs[r];
      size_t o = (size_t)(b*256+co)*4096 + y*64 + x;
      if (MODE==0){
        v = lrelu(v) + resid[o];
        outf[o] = v;
        outh[((size_t)((b*64+y)*64+x)<<8) + co] = (f16)v;  // NHWC for next conv
      } else {
        outf[o] = v;  // NCHW f32
      }
    }
  }
}

// ======================= instance-norm stats (NCHW f32) =======================
__global__ __launch_bounds__(256) void k_instats(const float* __restrict__ v, float2* __restrict__ st)
{
  int bc = blockIdx.x;
  const float* p = v + (size_t)bc*4096;
  int tid = threadIdx.x;
  float s=0.f, ss=0.f;
  #pragma unroll
  for (int it=0; it<4; ++it){
    float4 u = *(const float4*)(p + it*1024 + tid*4);
    s  += u.x+u.y+u.z+u.w;
    ss += u.x*u.x + u.y*u.y + u.z*u.z + u.w*u.w;
  }
  #pragma unroll
  for (int off=32; off; off>>=1){ s += __shfl_down(s, off, 64); ss += __shfl_down(ss, off, 64); }
  __shared__ float rs[4], rss[4];
  int wave = tid>>6, lane = tid&63;
  if (lane==0){ rs[wave]=s; rss[wave]=ss; }
  __syncthreads();
  if (tid==0){
    float S = rs[0]+rs[1]+rs[2]+rs[3], SS = rss[0]+rss[1]+rss[2]+rss[3];
    float mu = S*(1.f/4096.f);
    float var = SS*(1.f/4096.f) - mu*mu;
    st[bc] = make_float2(mu, rsqrtf(var + 1e-5f));
  }
}

// final: out += lrelu(IN(c2))  (both NCHW f32)
__global__ __launch_bounds__(256) void k_final(float* __restrict__ out, const float* __restrict__ c2,
                                               const float2* __restrict__ st)
{
  int i4 = blockIdx.x*256 + threadIdx.x;
  float2 s = st[i4>>10];
  float4 u = *(const float4*)(c2 + (size_t)i4*4);
  float4 o = *(const float4*)(out + (size_t)i4*4);
  o.x += lrelu((u.x - s.x)*s.y);
  o.y += lrelu((u.y - s.x)*s.y);
  o.z += lrelu((u.z - s.x)*s.y);
  o.w += lrelu((u.w - s.x)*s.y);
  *(float4*)(out + (size_t)i4*4) = o;
}

// ======================= launch =======================
extern "C" void kernel_launch(void* const* d_in, const int* in_sizes, int n_in,
                              void* d_out, int out_size, void* d_ws, size_t ws_size,
                              hipStream_t stream)
{
  const float* x    = (const float*)d_in[0];
  const float* mask = (const float*)d_in[1];
  const float* dis  = (const float*)d_in[2];
  const float* lapa = (const float*)d_in[3];
  const float* Wq   = (const float*)d_in[4];
  const float* bq   = (const float*)d_in[5];
  const float* Wk   = (const float*)d_in[6];
  const float* bk   = (const float*)d_in[7];
  const float* Wv   = (const float*)d_in[8];
  const float* bv   = (const float*)d_in[9];
  const float* nq   = (const float*)d_in[10];
  const float* nk   = (const float*)d_in[11];
  const float* nv   = (const float*)d_in[12];
  const float* Wo   = (const float*)d_in[13];
  const float* bo   = (const float*)d_in[14];
  const float* W1   = (const float*)d_in[15];
  const float* b1   = (const float*)d_in[16];
  const float* W2   = (const float*)d_in[17];
  const float* b2   = (const float*)d_in[18];

  char* w = (char*)d_ws;
  f16*   xh    = (f16*)(w + 0);            // 33.55 MB, dead after k_qkv
  f16*   Qp    = (f16*)(w + 33554432);
  f16*   Kp    = (f16*)(w + 67108864);
  f16*   Vt    = (f16*)(w + 100663296);
  f16*   attnb = (f16*)(w + 134217728);    // NHWC f16
  f16*   outbf = (f16*)(w + 0);            // alias xh
  float* c1    = (float*)(w + 33554432);   // alias Qp+Kp (dead after attn)
  f16*   y1    = (f16*)(w + 100663296);    // alias Vt
  float* c2    = (float*)(w + 33554432);   // alias c1
  f16*   wqh   = (f16*)(w + 167772160);
  f16*   wkh   = wqh + 65536;
  f16*   wvh   = wkh + 65536;
  f16*   wt0   = (f16*)(w + 168165376);
  f16*   wt1   = wt0 + 589824;
  f16*   wt2   = wt1 + 589824;
  float* pmk   = (float*)(w + 171704320);
  float2* st1  = (float2*)(w + 171720704);
  float2* st2  = (float2*)(w + 171753472);
  float* out   = (float*)d_out;

  k_prep1x1<<<768, 256, 0, stream>>>(Wq, Wk, Wv, wqh, wkh, wvh);
  k_prep3x3<<<6912, 256, 0, stream>>>(Wo, W1, W2, wt0, wt1, wt2);
  k_pmask<<<16, 256, 0, stream>>>(mask, pmk);
  k_nchw2nhwc<<<1024, 256, 0, stream>>>(x, nullptr, xh);
  k_qkv<<<3072, 256, 0, stream>>>(xh, wqh, wkh, wvh, bq, bk, bv, nq, nk, nv, Qp, Kp, Vt);
  k_attn<<<1024, 256, 0, stream>>>(Qp, Kp, Vt, dis, lapa, pmk, attnb);
  k_conv3<1,0><<<1024, 256, 0, stream>>>(attnb, wt0, bo, x, out, outbf);
  k_conv3<2,1><<<1024, 256, 0, stream>>>(outbf, wt1, b1, nullptr, c1, nullptr);
  k_instats<<<4096, 256, 0, stream>>>(c1, st1);
  k_nchw2nhwc<<<1024, 256, 0, stream>>>(c1, st1, y1);
  k_conv3<1,1><<<1024, 256, 0, stream>>>(y1, wt2, b2, nullptr, c2, nullptr);
  k_instats<<<4096, 256, 0, stream>>>(c2, st2);
  k_final<<<16384, 256, 0, stream>>>(out, c2, st2);
}

// Round 3
// 1068.697 us; speedup vs baseline: 1.4016x; 1.1544x over previous
//
#include <hip/hip_runtime.h>
#include <cstdint>
#include <cstddef>

typedef _Float16 f16;
typedef _Float16 f16x8 __attribute__((ext_vector_type(8)));
typedef _Float16 f16x4 __attribute__((ext_vector_type(4)));
typedef float    f32x4 __attribute__((ext_vector_type(4)));

#define MFMA16(a,b,c) __builtin_amdgcn_mfma_f32_16x16x32_f16((a),(b),(c),0,0,0)

__device__ __forceinline__ float lrelu(float v){ return v >= 0.f ? v : 0.2f*v; }

// ======================= prep kernels =======================

__global__ __launch_bounds__(256) void k_prep1x1(
    const float* __restrict__ wq, const float* __restrict__ wk, const float* __restrict__ wv,
    f16* __restrict__ oq, f16* __restrict__ ok, f16* __restrict__ ov)
{
  int i = blockIdx.x*256 + threadIdx.x;
  int sel = i >> 16, r = i & 65535;
  const float* s = sel==0 ? wq : (sel==1 ? wk : wv);
  f16* d = sel==0 ? oq : (sel==1 ? ok : ov);
  d[r] = (f16)s[r];
}

// 3x3 conv weights (co,ci,3,3) fp32 -> fp16 layout [tap][co][ci]
__global__ __launch_bounds__(256) void k_prep3x3(
    const float* __restrict__ w0, const float* __restrict__ w1, const float* __restrict__ w2,
    f16* __restrict__ o0, f16* __restrict__ o1, f16* __restrict__ o2)
{
  int i = blockIdx.x*256 + threadIdx.x;
  int sel = i / 589824;
  int r = i - sel*589824;
  int t = r >> 16; int rr = r & 65535; int co = rr >> 8; int ci = rr & 255;
  const float* s = sel==0 ? w0 : (sel==1 ? w1 : w2);
  f16* d = sel==0 ? o0 : (sel==1 ? o1 : o2);
  d[r] = (f16)s[(co*256 + ci)*9 + t];
}

__global__ __launch_bounds__(256) void k_pmask(const float* __restrict__ mask, float* __restrict__ pm)
{
  int t = blockIdx.x*256 + threadIdx.x;
  int b = t >> 8, n = t & 255;
  int y0 = (n>>4)<<2, x0 = (n&15)<<2;
  const float* mb = mask + b*4096;
  float s = 0.f;
  #pragma unroll
  for (int i=0;i<4;++i)
    #pragma unroll
    for (int j=0;j<4;++j) s += mb[(y0+i)*64 + x0+j];
  pm[t] = (s*(1.f/16.f) < 0.5f) ? 1.f : 0.f;
}

// ======================= NCHW f32 -> NHWC f16 (optional IN+lrelu) ===========
__global__ __launch_bounds__(256) void k_nchw2nhwc(
    const float* __restrict__ src, const float2* __restrict__ st, f16* __restrict__ dst)
{
  int idx = blockIdx.x;
  int y = idx & 63, b = idx >> 6;
  int tid = threadIdx.x;
  __shared__ f16 T[64*264];

  {
    const float* row = src + (size_t)(b*256+tid)*4096 + y*64;
    float mu = 0.f, ri = 1.f;
    bool doin = (st != nullptr);
    if (doin){ float2 s = st[b*256+tid]; mu = s.x; ri = s.y; }
    #pragma unroll
    for (int j=0;j<16;++j){
      float4 u = *(const float4*)(row + j*4);
      int x = j*4;
      float a0=(u.x-mu)*ri, a1=(u.y-mu)*ri, a2=(u.z-mu)*ri, a3=(u.w-mu)*ri;
      if (doin){ a0=lrelu(a0); a1=lrelu(a1); a2=lrelu(a2); a3=lrelu(a3); }
      T[(x+0)*264+tid]=(f16)a0; T[(x+1)*264+tid]=(f16)a1;
      T[(x+2)*264+tid]=(f16)a2; T[(x+3)*264+tid]=(f16)a3;
    }
  }
  __syncthreads();
  {
    int oct = tid & 31, pxl = tid >> 5;
    #pragma unroll
    for (int p=0;p<8;++p){
      int px = p*8 + pxl;
      *(uint4*)&dst[((size_t)((b*64+y)*64+px)<<8) + oct*8] = *(const uint4*)&T[px*264 + oct*8];
    }
  }
}

// ======================= QKV 1x1-conv GEMM (NHWC input) =======================
// grid: ((sel*16 + b)*4 + cot)*16 + yt ; block 256. 64co x (4y x 64x).
// Epilogue: LDS transpose -> coalesced patchified stores.
__global__ __launch_bounds__(256) void k_qkv(
    const f16* __restrict__ xh,
    const f16* __restrict__ wq, const f16* __restrict__ wk, const f16* __restrict__ wv,
    const float* __restrict__ bq, const float* __restrict__ bk, const float* __restrict__ bv,
    const float* __restrict__ nq, const float* __restrict__ nk, const float* __restrict__ nv,
    f16* __restrict__ Qp, f16* __restrict__ Kp, f16* __restrict__ Vt)
{
  int idx = blockIdx.x;
  int yt  = idx & 15; idx >>= 4;
  int cot = idx & 3;  idx >>= 2;
  int b   = idx & 15; idx >>= 4;
  int sel = idx;
  int tid = threadIdx.x;
  int wave = tid>>6, lane = tid&63, quad = lane>>4, l16 = lane&15;
  int co0 = cot*64, y0 = yt*4;

  const f16*  W    = sel==0 ? wq : (sel==1 ? wk : wv);
  const float* bias= sel==0 ? bq : (sel==1 ? bk : bv);
  const float* nz  = sel==0 ? nq : (sel==1 ? nk : nv);

  // smem: K-loop phase: Al = [0,2560), Bl = [2560,10752). Epilogue: Sl = [0,16896)
  __shared__ f16 smem[64*264];
  f16* Al = smem;
  f16* Bl = smem + 2560;

  f32x4 acc[16];
  #pragma unroll
  for (int i=0;i<16;++i){ acc[i][0]=0.f; acc[i][1]=0.f; acc[i][2]=0.f; acc[i][3]=0.f; }

  for (int kc=0;kc<8;++kc){
    int ci0 = kc*32;
    {
      int aco = tid>>2, ap = (tid&3)*8;
      *(uint4*)&Al[aco*40+ap] = *(const uint4*)&W[((co0+aco)<<8) + ci0 + ap];
    }
    #pragma unroll
    for (int p=0;p<4;++p){
      int i = p*256 + tid;
      int px = i>>2, oct = i&3;
      uint4 v = *(const uint4*)&xh[((size_t)((b*64 + y0 + (px>>6))*64 + (px&63))<<8) + ci0 + oct*8];
      *(uint4*)&Bl[px*32 + ((oct ^ (px&3))<<3)] = v;
    }
    __syncthreads();
    f16x8 af = *(const f16x8*)&Al[(wave*16+l16)*40 + quad*8];
    #pragma unroll
    for (int nt=0;nt<16;++nt){
      int bidx = (nt>>2)*64 + (nt&3)*16 + l16;
      f16x8 bf = *(const f16x8*)&Bl[bidx*32 + ((quad ^ (bidx&3))<<3)];
      acc[nt] = MFMA16(af, bf, acc[nt]);
    }
    __syncthreads();
  }

  // ---- epilogue: regs -> LDS (transpose), LDS -> global (coalesced) ----
  int cob = co0 + wave*16 + quad*4;
  int h0 = cot*4, pr = yt;
  #pragma unroll
  for (int nt=0;nt<16;++nt){
    int y = y0 + (nt>>2), x = (nt&3)*16 + l16;
    int n_ = (nt&3)*4 + (l16>>2);                       // patch col 0..15
    int ddb = (quad<<6) + ((nt>>2)<<2) + (l16&3);       // dd minus r*16
    #pragma unroll
    for (int r=0;r<4;++r){
      int co = cob + r;
      float v = acc[nt][r] + bias[co] + nz[(size_t)(b*256+co)*4096 + y*64 + x];
      int dd = ddb + (r<<4);
      if (sel < 2) smem[(wave*16 + n_)*264 + dd] = (f16)v;   // [h'][n'][dd]
      else         smem[(wave<<12) + (dd<<4) + n_] = (f16)v; // [h'][dd][n']
    }
  }
  __syncthreads();
  if (sel < 2){
    f16* dst = sel==0 ? Qp : Kp;
    #pragma unroll
    for (int pass=0; pass<8; ++pass){
      int row = pass*8 + (tid>>5);        // 0..63 : h'=row>>4, n'=row&15
      int ch  = tid & 31;
      uint4 v = *(const uint4*)&smem[row*264 + ch*8];
      *(uint4*)&dst[((b*16 + h0 + (row>>4))<<16) + ((pr*16 + (row&15))<<8) + ch*8] = v;
    }
  } else {
    #pragma unroll
    for (int pass=0; pass<8; ++pass){
      int i = pass*256 + tid;
      int rw = i>>1, half = i&1;          // rw = h'*256 + dd
      uint4 v = *(const uint4*)&smem[(rw<<4) + (half<<3)];
      *(uint4*)&Vt[((b*16 + h0 + (rw>>8))<<16) + ((rw&255)<<8) + pr*16 + (half<<3)] = v;
    }
  }
}

// ======================= attention =======================
__global__ __launch_bounds__(256) void k_attn(
    const f16* __restrict__ Qp, const f16* __restrict__ Kp, const f16* __restrict__ Vt,
    const float* __restrict__ dis, const float* __restrict__ lap_a,
    const float* __restrict__ pm, f16* __restrict__ attn)
{
  int idx = blockIdx.x;
  int nt = idx & 3; idx >>= 2;
  int h  = idx & 15; idx >>= 4;
  int b  = idx;
  int tid = threadIdx.x, wave = tid>>6, lane = tid&63, quad = lane>>4, l16 = lane&15;
  int n0 = nt*64;
  int bh = (b*16 + h) << 16;

  // smem: Ql = [0,16896), KVl = [16896,25344); epilogue: Ol = [0, 24576)
  __shared__ f16 smem[25344];
  f16* Ql  = smem;
  f16* KVl = smem + 16896;

  {
    int row = tid>>2, part = (tid&3)*64;
    const uint4* s = (const uint4*)&Qp[bh + ((n0+row)<<8) + part];
    uint4* d = (uint4*)&Ql[row*264 + part];
    #pragma unroll
    for (int j=0;j<8;++j) d[j] = s[j];
  }

  float splus = log1pf(expf(lap_a[0]));

  f32x4 sacc[16];
  #pragma unroll
  for (int i=0;i<16;++i){ sacc[i][0]=0.f; sacc[i][1]=0.f; sacc[i][2]=0.f; sacc[i][3]=0.f; }

  #pragma unroll
  for (int mc=0; mc<8; ++mc){
    __syncthreads();
    {
      int row = tid>>3, part = (tid&7)*32;
      const uint4* s = (const uint4*)&Kp[bh + ((mc*32+row)<<8) + part];
      uint4* d = (uint4*)&KVl[row*264 + part];
      #pragma unroll
      for (int j=0;j<4;++j) d[j] = s[j];
    }
    __syncthreads();
    #pragma unroll
    for (int kk=0;kk<8;++kk){
      f16x8 af = *(const f16x8*)&Ql[(wave*16+l16)*264 + kk*32 + quad*8];
      #pragma unroll
      for (int j=0;j<2;++j){
        f16x8 bf = *(const f16x8*)&KVl[(j*16+l16)*264 + kk*32 + quad*8];
        sacc[mc*2+j] = MFMA16(af, bf, sacc[mc*2+j]);
      }
    }
  }

  int nrow_base = wave*16 + quad*4;
  float pmv[16];
  #pragma unroll
  for (int t=0;t<16;++t) pmv[t] = pm[b*256 + t*16 + l16];

  #pragma unroll
  for (int r=0;r<4;++r){
    int n = n0 + nrow_base + r;
    float sv[16];
    float mx = -1e30f;
    #pragma unroll
    for (int t=0;t<16;++t){
      float s = sacc[t][r];
      s = (s + splus * dis[n*256 + t*16 + l16]) * 0.0625f;
      s = (pmv[t] > 0.5f) ? -1e30f : s;
      sv[t] = s;
      mx = fmaxf(mx, s);
    }
    #pragma unroll
    for (int off=1; off<16; off<<=1) mx = fmaxf(mx, __shfl_xor(mx, off, 64));
    float sum = 0.f;
    #pragma unroll
    for (int t=0;t<16;++t){ float e = __expf(sv[t]-mx); sv[t]=e; sum += e; }
    #pragma unroll
    for (int off=1; off<16; off<<=1) sum += __shfl_xor(sum, off, 64);
    float inv = 1.f/sum;
    #pragma unroll
    for (int t=0;t<16;++t) Ql[(nrow_base + r)*264 + t*16 + l16] = (f16)(sv[t]*inv);
  }

  // O = P V, all 8 dd-chunks accumulated in registers
  f32x4 oacc[16];
  #pragma unroll
  for (int i=0;i<16;++i){ oacc[i][0]=0.f; oacc[i][1]=0.f; oacc[i][2]=0.f; oacc[i][3]=0.f; }

  for (int dc=0; dc<8; ++dc){
    __syncthreads();
    {
      int row = tid>>3, part = (tid&7)*32;
      const uint4* s = (const uint4*)&Vt[bh + ((dc*32+row)<<8) + part];
      uint4* d = (uint4*)&KVl[row*264 + part];
      #pragma unroll
      for (int j=0;j<4;++j) d[j] = s[j];
    }
    __syncthreads();
    #pragma unroll
    for (int kk=0;kk<8;++kk){
      f16x8 af = *(const f16x8*)&Ql[(wave*16+l16)*264 + kk*32 + quad*8];
      #pragma unroll
      for (int j=0;j<2;++j){
        f16x8 bf = *(const f16x8*)&KVl[(j*16+l16)*264 + kk*32 + quad*8];
        oacc[dc*2+j] = MFMA16(af, bf, oacc[dc*2+j]);
      }
    }
  }

  // ---- epilogue: regs -> LDS [y'][x][c' pad24] -> coalesced NHWC stores ----
  __syncthreads();
  #pragma unroll
  for (int dc=0; dc<8; ++dc){
    #pragma unroll
    for (int j=0;j<2;++j){
      int dd = dc*32 + j*16 + l16;
      int c_ = dd>>4;
      int pi = (dd>>2)&3, pj = dd&3;
      #pragma unroll
      for (int r=0;r<4;++r){
        int nl = nrow_base + r;
        int y_ = ((nl>>4)<<2) + pi;
        int x  = ((nl&15)<<2) + pj;
        smem[(y_*64 + x)*24 + c_] = (f16)oacc[dc*2+j][r];
      }
    }
  }
  __syncthreads();
  #pragma unroll
  for (int p=0;p<4;++p){
    int pix = p*256 + tid;
    int y_ = pix>>6, x = pix&63;
    uint4 v0 = *(const uint4*)&smem[pix*24];
    uint4 v1 = *(const uint4*)&smem[pix*24 + 8];
    size_t o = ((size_t)((b*64 + nt*16 + y_)*64 + x)<<8) + h*16;
    *(uint4*)&attn[o]     = v0;
    *(uint4*)&attn[o + 8] = v1;
  }
}

// ======================= 3x3 conv (implicit GEMM, NHWC input) ================
template<int DIL, int MODE>
__global__ __launch_bounds__(256) void k_conv3(
    const f16* __restrict__ in, const f16* __restrict__ Wt, const float* __restrict__ bias,
    const float* __restrict__ resid, float* __restrict__ outf, f16* __restrict__ outh)
{
  int idx = blockIdx.x;
  int yt  = idx & 15; idx >>= 4;
  int cot = idx & 3;  idx >>= 2;
  int b   = idx;
  int y0 = yt*4, co0 = cot*64;
  int tid = threadIdx.x;
  int wave = tid>>6, lane = tid&63, quad = lane>>4, l16 = lane&15;

  __shared__ f16 Al[3*64*40];
  __shared__ f16 Bl[4*68*32];

  f32x4 acc[16];
  #pragma unroll
  for (int i=0;i<16;++i){ acc[i][0]=0.f; acc[i][1]=0.f; acc[i][2]=0.f; acc[i][3]=0.f; }

  constexpr int PXR = 64 + 2*DIL;
  constexpr int NU4 = 16*PXR;

  for (int ky=0; ky<3; ++ky){
    int yb = y0 + DIL*(ky-1);
    for (int kc=0; kc<8; ++kc){
      int ci0 = kc*32;
      {
        int aco = tid>>2, ap = (tid&3)*8;
        #pragma unroll
        for (int kx=0;kx<3;++kx)
          *(uint4*)&Al[kx*2560 + aco*40 + ap] =
              *(const uint4*)&Wt[((ky*3+kx)<<16) + ((co0+aco)<<8) + ci0 + ap];
      }
      #pragma unroll
      for (int p=0;p<5;++p){
        int i = p*256 + tid;
        if (i < NU4){
          int px = i>>2, oct = i&3;
          int yr = px / PXR, xp = px - yr*PXR;
          int yy = yb + yr, xx = xp - DIL;
          uint4 v = make_uint4(0u,0u,0u,0u);
          if (yy>=0 && yy<64 && xx>=0 && xx<64)
            v = *(const uint4*)&in[((size_t)((b*64+yy)*64+xx)<<8) + ci0 + oct*8];
          int si = yr*68 + xp;
          *(uint4*)&Bl[si*32 + ((oct ^ (si&3))<<3)] = v;
        }
      }
      __syncthreads();
      #pragma unroll
      for (int kx=0;kx<3;++kx){
        f16x8 af = *(const f16x8*)&Al[kx*2560 + (wave*16+l16)*40 + quad*8];
        #pragma unroll
        for (int nt=0;nt<16;++nt){
          int bidx = (nt>>2)*68 + (nt&3)*16 + l16 + kx*DIL;
          f16x8 bf = *(const f16x8*)&Bl[bidx*32 + ((quad ^ (bidx&3))<<3)];
          acc[nt] = MFMA16(af, bf, acc[nt]);
        }
      }
      __syncthreads();
    }
  }

  int cob = co0 + wave*16 + quad*4;
  float bs[4];
  #pragma unroll
  for (int r=0;r<4;++r) bs[r] = bias[cob+r];
  #pragma unroll
  for (int nt=0;nt<16;++nt){
    int y = y0 + (nt>>2), x = (nt&3)*16 + l16;
    #pragma unroll
    for (int r=0;r<4;++r){
      int co = cob + r;
      float v = acc[nt][r] + bs[r];
      size_t o = (size_t)(b*256+co)*4096 + y*64 + x;
      if (MODE==0){
        v = lrelu(v) + resid[o];
        outf[o] = v;
        outh[((size_t)((b*64+y)*64+x)<<8) + co] = (f16)v;
      } else {
        outf[o] = v;
      }
    }
  }
}

// ======================= instance-norm stats (NCHW f32) =======================
__global__ __launch_bounds__(256) void k_instats(const float* __restrict__ v, float2* __restrict__ st)
{
  int bc = blockIdx.x;
  const float* p = v + (size_t)bc*4096;
  int tid = threadIdx.x;
  float s=0.f, ss=0.f;
  #pragma unroll
  for (int it=0; it<4; ++it){
    float4 u = *(const float4*)(p + it*1024 + tid*4);
    s  += u.x+u.y+u.z+u.w;
    ss += u.x*u.x + u.y*u.y + u.z*u.z + u.w*u.w;
  }
  #pragma unroll
  for (int off=32; off; off>>=1){ s += __shfl_down(s, off, 64); ss += __shfl_down(ss, off, 64); }
  __shared__ float rs[4], rss[4];
  int wave = tid>>6, lane = tid&63;
  if (lane==0){ rs[wave]=s; rss[wave]=ss; }
  __syncthreads();
  if (tid==0){
    float S = rs[0]+rs[1]+rs[2]+rs[3], SS = rss[0]+rss[1]+rss[2]+rss[3];
    float mu = S*(1.f/4096.f);
    float var = SS*(1.f/4096.f) - mu*mu;
    st[bc] = make_float2(mu, rsqrtf(var + 1e-5f));
  }
}

// final: out += lrelu(IN(c2))
__global__ __launch_bounds__(256) void k_final(float* __restrict__ out, const float* __restrict__ c2,
                                               const float2* __restrict__ st)
{
  int i4 = blockIdx.x*256 + threadIdx.x;
  float2 s = st[i4>>10];
  float4 u = *(const float4*)(c2 + (size_t)i4*4);
  float4 o = *(const float4*)(out + (size_t)i4*4);
  o.x += lrelu((u.x - s.x)*s.y);
  o.y += lrelu((u.y - s.x)*s.y);
  o.z += lrelu((u.z - s.x)*s.y);
  o.w += lrelu((u.w - s.x)*s.y);
  *(float4*)(out + (size_t)i4*4) = o;
}

// ======================= launch =======================
extern "C" void kernel_launch(void* const* d_in, const int* in_sizes, int n_in,
                              void* d_out, int out_size, void* d_ws, size_t ws_size,
                              hipStream_t stream)
{
  const float* x    = (const float*)d_in[0];
  const float* mask = (const float*)d_in[1];
  const float* dis  = (const float*)d_in[2];
  const float* lapa = (const float*)d_in[3];
  const float* Wq   = (const float*)d_in[4];
  const float* bq   = (const float*)d_in[5];
  const float* Wk   = (const float*)d_in[6];
  const float* bk   = (const float*)d_in[7];
  const float* Wv   = (const float*)d_in[8];
  const float* bv   = (const float*)d_in[9];
  const float* nq   = (const float*)d_in[10];
  const float* nk   = (const float*)d_in[11];
  const float* nv   = (const float*)d_in[12];
  const float* Wo   = (const float*)d_in[13];
  const float* bo   = (const float*)d_in[14];
  const float* W1   = (const float*)d_in[15];
  const float* b1   = (const float*)d_in[16];
  const float* W2   = (const float*)d_in[17];
  const float* b2   = (const float*)d_in[18];

  char* w = (char*)d_ws;
  f16*   xh    = (f16*)(w + 0);
  f16*   Qp    = (f16*)(w + 33554432);
  f16*   Kp    = (f16*)(w + 67108864);
  f16*   Vt    = (f16*)(w + 100663296);
  f16*   attnb = (f16*)(w + 134217728);
  f16*   outbf = (f16*)(w + 0);
  float* c1    = (float*)(w + 33554432);
  f16*   y1    = (f16*)(w + 100663296);
  float* c2    = (float*)(w + 33554432);
  f16*   wqh   = (f16*)(w + 167772160);
  f16*   wkh   = wqh + 65536;
  f16*   wvh   = wkh + 65536;
  f16*   wt0   = (f16*)(w + 168165376);
  f16*   wt1   = wt0 + 589824;
  f16*   wt2   = wt1 + 589824;
  float* pmk   = (float*)(w + 171704320);
  float2* st1  = (float2*)(w + 171720704);
  float2* st2  = (float2*)(w + 171753472);
  float* out   = (float*)d_out;

  k_prep1x1<<<768, 256, 0, stream>>>(Wq, Wk, Wv, wqh, wkh, wvh);
  k_prep3x3<<<6912, 256, 0, stream>>>(Wo, W1, W2, wt0, wt1, wt2);
  k_pmask<<<16, 256, 0, stream>>>(mask, pmk);
  k_nchw2nhwc<<<1024, 256, 0, stream>>>(x, nullptr, xh);
  k_qkv<<<3072, 256, 0, stream>>>(xh, wqh, wkh, wvh, bq, bk, bv, nq, nk, nv, Qp, Kp, Vt);
  k_attn<<<1024, 256, 0, stream>>>(Qp, Kp, Vt, dis, lapa, pmk, attnb);
  k_conv3<1,0><<<1024, 256, 0, stream>>>(attnb, wt0, bo, x, out, outbf);
  k_conv3<2,1><<<1024, 256, 0, stream>>>(outbf, wt1, b1, nullptr, c1, nullptr);
  k_instats<<<4096, 256, 0, stream>>>(c1, st1);
  k_nchw2nhwc<<<1024, 256, 0, stream>>>(c1, st1, y1);
  k_conv3<1,1><<<1024, 256, 0, stream>>>(y1, wt2, b2, nullptr, c2, nullptr);
  k_instats<<<4096, 256, 0, stream>>>(c2, st2);
  k_final<<<16384, 256, 0, stream>>>(out, c2, st2);
}